// Round 11
// baseline (483.422 us; speedup 1.0000x reference)
//
#include <hip/hip_runtime.h>

#define E_EDGES 1600000
#define BM 64
#define TPB 256
#define NTILES (E_EDGES / BM)   // 25000 exactly
#define GRID 768                // 3 blocks/CU (LDS 3x40KB, VGPR cap 170)
#define WOFF 40960              // shorts reserved for weights in d_ws
#define XBF_SHORTS (100000 * 64)

typedef short s16x8 __attribute__((ext_vector_type(8)));
typedef float f32x4 __attribute__((ext_vector_type(4)));
typedef unsigned int u32x2 __attribute__((ext_vector_type(2)));
typedef unsigned int u32x4 __attribute__((ext_vector_type(4)));

__device__ __forceinline__ unsigned short f2bf(float f) {
    unsigned int u = __builtin_bit_cast(unsigned int, f);
    u += 0x7FFFu + ((u >> 16) & 1u);   // RNE
    return (unsigned short)(u >> 16);
}

// v_cvt_pk_bf16_f32: dst.lo = bf16(lo), dst.hi = bf16(hi), RNE
__device__ __forceinline__ unsigned cvtpk(float lo, float hi) {
    unsigned r;
    asm("v_cvt_pk_bf16_f32 %0, %1, %2" : "=v"(r) : "v"(lo), "v"(hi));
    return r;
}

__device__ __forceinline__ s16x8 pack8(float4 a, float4 b) {
    s16x8 r;
    r[0] = (short)f2bf(a.x); r[1] = (short)f2bf(a.y);
    r[2] = (short)f2bf(a.z); r[3] = (short)f2bf(a.w);
    r[4] = (short)f2bf(b.x); r[5] = (short)f2bf(b.y);
    r[6] = (short)f2bf(b.z); r[7] = (short)f2bf(b.w);
    return r;
}

// d_ws layout (shorts): [0,16384) Wnnn^T [128o][128i]; [16384,24576) Wroot^T [128o][64i];
//                       [24576,40960) Wout^T [128o][128i]; [40960, +6.4M) x as bf16
__global__ void prep_w(const float* __restrict__ Wn, const float* __restrict__ Wr,
                       const float* __restrict__ Wo, unsigned short* __restrict__ wt) {
    int t = blockIdx.x * 256 + threadIdx.x;
    if (t < 16384) {
        int o = t >> 7, i = t & 127;
        wt[t] = f2bf(Wn[i * 128 + o]);
    } else if (t < 24576) {
        int q = t - 16384;
        int o = q >> 6, i = q & 63;
        wt[t] = f2bf(Wr[i * 128 + o]);
    } else if (t < 40960) {
        int q = t - 24576;
        int o = q >> 7, i = q & 127;
        wt[t] = f2bf(Wo[i * 128 + o]);
    }
}

__global__ void prep_x(const float* __restrict__ x, unsigned short* __restrict__ xb) {
    int i = blockIdx.x * 256 + threadIdx.x;    // 800000 chunks of 8 floats
    if (i < XBF_SHORTS / 8) {
        const float4* p = (const float4*)(x + (size_t)i * 8);
        *(s16x8*)(xb + (size_t)i * 8) = pack8(p[0], p[1]);
    }
}

// Swapped-operand MFMA: mfma(A = W^T frag [n][k], B = data frag [k][e]).
// C-frag: col(lane&15)=e, row((lane>>4)*4+j)=n -> 4 consecutive n per lane.
// LDS chunk-major [kq][e][8 shorts]: all accesses linear, bank-even.
// nt=2 n-blocking: 4 waves, wave w owns n in [w*32, w*32+32) as two 16-n
// subtiles -> every LDS B-frag read feeds TWO MFMAs (halves LDS read traffic).
// Biases pre-loaded into MFMA accumulator init (saves the adds).
template<bool XBF>
__global__ __launch_bounds__(TPB, 3) void edge_mlp(
    const float* __restrict__ x, const unsigned short* __restrict__ xb,
    const int* __restrict__ eidx, const float* __restrict__ ea,
    const float* __restrict__ bn_g, const float* __restrict__ br_g,
    const float* __restrict__ bo_g,
    const unsigned short* __restrict__ wt, float* __restrict__ out)
{
    __shared__ unsigned short sh_pair[16 * 64 * 8];  // [kq][e][8], 16 KB
    __shared__ unsigned short sh_ea[8 * 64 * 8];     // [kq][e][8],  8 KB
    __shared__ unsigned short sh_hid[16 * 64 * 8];   // [kq][e][8], 16 KB

    const int tid = threadIdx.x;
    const int w   = tid >> 6;        // wave 0..3 -> n in [w*32, w*32+32)
    const int ln  = tid & 63;
    const int lc  = ln & 15;
    const int q   = ln >> 4;         // 0..3

    // gather ownership: thread owns edge-row r; pair quarter sub (4 chunks = 64B);
    // ea 16-float segment es (-> 2 chunks)
    const int r   = tid >> 2;        // 0..63
    const int sub = tid & 3;         // 0,1: src halves; 2,3: dst halves
    const int ihalf = (sub < 2) ? 0 : E_EDGES;
    const int xo  = (sub & 1) * 32;  // short offset within node row
    const int es  = tid & 3;

    const unsigned short* Wn = wt;
    const unsigned short* Wr = wt + 16384;
    const unsigned short* Wo = wt + 24576;

    // --- pinned weight A-fragments (80 VGPR) ---
    s16x8 wn[2][4], wr[2][2], wo[2][4];
    #pragma unroll
    for (int nt = 0; nt < 2; ++nt) {
        const int n0 = w * 32 + nt * 16 + lc;
        #pragma unroll
        for (int kk = 0; kk < 4; ++kk) wn[nt][kk] = *(const s16x8*)(Wn + n0 * 128 + kk * 32 + q * 8);
        #pragma unroll
        for (int kk = 0; kk < 2; ++kk) wr[nt][kk] = *(const s16x8*)(Wr + n0 * 64 + kk * 32 + q * 8);
        #pragma unroll
        for (int kk = 0; kk < 4; ++kk) wo[nt][kk] = *(const s16x8*)(Wo + n0 * 128 + kk * 32 + q * 8);
    }
    // biases as f32x4 (used as MFMA C-init)
    f32x4 bn4[2], br4[2], bo4[2];
    #pragma unroll
    for (int nt = 0; nt < 2; ++nt) {
        const int nb = w * 32 + nt * 16 + q * 4;
        bn4[nt] = *(const f32x4*)(bn_g + nb);
        br4[nt] = *(const f32x4*)(br_g + nb);
        bo4[nt] = *(const f32x4*)(bo_g + nb);
    }

    // --- pipeline regs: tile t+1 data, tile t+2 index ---
    s16x8 pr[4];                     // XBF: 64B contiguous slice of node row
    float4 pf[8];                    // fallback: 128B fp32 slice
    f32x4 ef[4];                     // ea 64B slice
    int ic, ic_n;

    int tile = blockIdx.x;

    // prologue: tile-0 data, tile-1 index
    ic = eidx[ihalf + tile * BM + r];
    if constexpr (XBF) {
        const s16x8* xp = (const s16x8*)(xb + (size_t)ic * 64 + xo);
        #pragma unroll
        for (int k = 0; k < 4; ++k) pr[k] = xp[k];
    } else {
        const float4* xp = (const float4*)(x + (size_t)ic * 64 + xo);
        #pragma unroll
        for (int k = 0; k < 8; ++k) pf[k] = xp[k];
    }
    {
        const f32x4* ep = (const f32x4*)(ea + (size_t)(tile * BM + r) * 64 + es * 16);
        #pragma unroll
        for (int k = 0; k < 4; ++k) ef[k] = ep[k];
    }
    {
        int t1 = (tile + GRID < NTILES) ? tile + GRID : tile;
        ic_n = eidx[ihalf + t1 * BM + r];
    }

    for (; tile < NTILES; tile += GRID) {
        const int base = tile * BM;
        const int tn  = (tile + GRID < NTILES) ? tile + GRID : tile;
        const int tnn = (tn + GRID < NTILES) ? tn + GRID : tn;

        // --- A: drain prefetch -> LDS (chunk-major) ---
        if constexpr (XBF) {
            #pragma unroll
            for (int i = 0; i < 4; ++i)
                *(s16x8*)((char*)sh_pair + (sub * 4 + i) * 1024 + r * 16) = pr[i];
        } else {
            #pragma unroll
            for (int i = 0; i < 4; ++i)
                *(s16x8*)((char*)sh_pair + (sub * 4 + i) * 1024 + r * 16) = pack8(pf[2 * i], pf[2 * i + 1]);
        }
        #pragma unroll
        for (int i = 0; i < 2; ++i) {
            u32x4 v;
            v[0] = cvtpk(ef[2 * i][0], ef[2 * i][1]);
            v[1] = cvtpk(ef[2 * i][2], ef[2 * i][3]);
            v[2] = cvtpk(ef[2 * i + 1][0], ef[2 * i + 1][1]);
            v[3] = cvtpk(ef[2 * i + 1][2], ef[2 * i + 1][3]);
            *(u32x4*)((char*)sh_ea + (es * 2 + i) * 1024 + r * 16) = v;
        }

        // --- C: issue tile t+1 loads (latency hidden under D+E) ---
        ic = ic_n;
        if constexpr (XBF) {
            const s16x8* xp = (const s16x8*)(xb + (size_t)ic * 64 + xo);
            #pragma unroll
            for (int k = 0; k < 4; ++k) pr[k] = xp[k];
        } else {
            const float4* xp = (const float4*)(x + (size_t)ic * 64 + xo);
            #pragma unroll
            for (int k = 0; k < 8; ++k) pf[k] = xp[k];
        }
        {
            const f32x4* ep = (const f32x4*)(ea + (size_t)(tn * BM + r) * 64 + es * 16);
            #pragma unroll
            for (int k = 0; k < 4; ++k) ef[k] = ep[k];
        }
        ic_n = eidx[ihalf + tnn * BM + r];

        __syncthreads();   // barrier1: pair/ea ready; hid E(t-1) reads done

        // --- D: layer 1 -> sh_hid ---
        #pragma unroll
        for (int m = 0; m < 4; ++m) {
            const int e = m * 16 + lc;
            s16x8 g0 = *(const s16x8*)((const char*)sh_pair + (0 * 4 + q) * 1024 + e * 16);
            s16x8 g1 = *(const s16x8*)((const char*)sh_pair + (1 * 4 + q) * 1024 + e * 16);
            s16x8 g2 = *(const s16x8*)((const char*)sh_pair + (2 * 4 + q) * 1024 + e * 16);
            s16x8 g3 = *(const s16x8*)((const char*)sh_pair + (3 * 4 + q) * 1024 + e * 16);
            s16x8 e0 = *(const s16x8*)((const char*)sh_ea + (0 * 4 + q) * 1024 + e * 16);
            s16x8 e1 = *(const s16x8*)((const char*)sh_ea + (1 * 4 + q) * 1024 + e * 16);
            f32x4 a1[2], a2[2];
            #pragma unroll
            for (int nt = 0; nt < 2; ++nt) { a1[nt] = bn4[nt]; a2[nt] = br4[nt]; }
            #pragma unroll
            for (int nt = 0; nt < 2; ++nt) {
                a1[nt] = __builtin_amdgcn_mfma_f32_16x16x32_bf16(wn[nt][0], g0, a1[nt], 0, 0, 0);
                a1[nt] = __builtin_amdgcn_mfma_f32_16x16x32_bf16(wn[nt][1], g1, a1[nt], 0, 0, 0);
                a1[nt] = __builtin_amdgcn_mfma_f32_16x16x32_bf16(wn[nt][2], g2, a1[nt], 0, 0, 0);
                a1[nt] = __builtin_amdgcn_mfma_f32_16x16x32_bf16(wn[nt][3], g3, a1[nt], 0, 0, 0);
                a2[nt] = __builtin_amdgcn_mfma_f32_16x16x32_bf16(wr[nt][0], e0, a2[nt], 0, 0, 0);
                a2[nt] = __builtin_amdgcn_mfma_f32_16x16x32_bf16(wr[nt][1], e1, a2[nt], 0, 0, 0);
            }
            #pragma unroll
            for (int nt = 0; nt < 2; ++nt) {
                float h0 = fmaxf(a1[nt][0], 0.f) + fmaxf(a2[nt][0], 0.f);
                float h1 = fmaxf(a1[nt][1], 0.f) + fmaxf(a2[nt][1], 0.f);
                float h2 = fmaxf(a1[nt][2], 0.f) + fmaxf(a2[nt][2], 0.f);
                float h3 = fmaxf(a1[nt][3], 0.f) + fmaxf(a2[nt][3], 0.f);
                u32x2 hv;
                hv[0] = cvtpk(h0, h1);
                hv[1] = cvtpk(h2, h3);
                // n0 = w*32+nt*16+q*4 -> chunk = w*4+nt*2+(q>>1), byte = (q&1)*8
                *(u32x2*)((char*)sh_hid + (w * 4 + nt * 2 + (q >> 1)) * 1024 + e * 16 + (q & 1) * 8) = hv;
            }
        }
        __syncthreads();   // barrier2: hid ready; pair/ea reads done before A(t+1)

        // --- E: layer 2 -> out ---
        #pragma unroll
        for (int m = 0; m < 4; ++m) {
            const int e = m * 16 + lc;
            s16x8 g0 = *(const s16x8*)((const char*)sh_hid + (0 * 4 + q) * 1024 + e * 16);
            s16x8 g1 = *(const s16x8*)((const char*)sh_hid + (1 * 4 + q) * 1024 + e * 16);
            s16x8 g2 = *(const s16x8*)((const char*)sh_hid + (2 * 4 + q) * 1024 + e * 16);
            s16x8 g3 = *(const s16x8*)((const char*)sh_hid + (3 * 4 + q) * 1024 + e * 16);
            f32x4 a3[2];
            #pragma unroll
            for (int nt = 0; nt < 2; ++nt) a3[nt] = bo4[nt];
            #pragma unroll
            for (int nt = 0; nt < 2; ++nt) {
                a3[nt] = __builtin_amdgcn_mfma_f32_16x16x32_bf16(wo[nt][0], g0, a3[nt], 0, 0, 0);
                a3[nt] = __builtin_amdgcn_mfma_f32_16x16x32_bf16(wo[nt][1], g1, a3[nt], 0, 0, 0);
                a3[nt] = __builtin_amdgcn_mfma_f32_16x16x32_bf16(wo[nt][2], g2, a3[nt], 0, 0, 0);
                a3[nt] = __builtin_amdgcn_mfma_f32_16x16x32_bf16(wo[nt][3], g3, a3[nt], 0, 0, 0);
            }
            #pragma unroll
            for (int nt = 0; nt < 2; ++nt) {
                f32x4 o;
                o[0] = fmaxf(a3[nt][0], 0.f);
                o[1] = fmaxf(a3[nt][1], 0.f);
                o[2] = fmaxf(a3[nt][2], 0.f);
                o[3] = fmaxf(a3[nt][3], 0.f);
                *(f32x4*)(out + (size_t)(base + e) * 128 + w * 32 + nt * 16 + q * 4) = o;
            }
        }
    }
}

extern "C" void kernel_launch(void* const* d_in, const int* in_sizes, int n_in,
                              void* d_out, int out_size, void* d_ws, size_t ws_size,
                              hipStream_t stream) {
    const float* x   = (const float*)d_in[0];
    const int*   ei  = (const int*)d_in[1];
    const float* ea  = (const float*)d_in[2];
    const float* Wn  = (const float*)d_in[3];
    const float* bn  = (const float*)d_in[4];
    const float* Wr  = (const float*)d_in[5];
    const float* br  = (const float*)d_in[6];
    const float* Wo  = (const float*)d_in[7];
    const float* bo  = (const float*)d_in[8];
    float* out = (float*)d_out;
    unsigned short* wt = (unsigned short*)d_ws;

    const bool xbf = ws_size >= (size_t)(WOFF + XBF_SHORTS) * sizeof(unsigned short);

    prep_w<<<160, 256, 0, stream>>>(Wn, Wr, Wo, wt);
    if (xbf) {
        prep_x<<<XBF_SHORTS / 8 / 256, 256, 0, stream>>>(x, wt + WOFF);
        edge_mlp<true><<<GRID, TPB, 0, stream>>>(x, wt + WOFF, ei, ea, bn, br, bo, wt, out);
    } else {
        edge_mlp<false><<<GRID, TPB, 0, stream>>>(x, nullptr, ei, ea, bn, br, bo, wt, out);
    }
}

// Round 12
// 292.578 us; speedup vs baseline: 1.6523x; 1.6523x over previous
//
#include <hip/hip_runtime.h>

#define E_EDGES 1600000
#define BM 64
#define TPB 512
#define NTILES (E_EDGES / BM)   // 25000 exactly
#define GRID 1024               // 4 blocks/CU: LDS 4x40KB = 160KB, VGPR<=128
#define WOFF 40960              // shorts reserved for weights in d_ws
#define XBF_SHORTS (100000 * 64)

typedef short s16x8 __attribute__((ext_vector_type(8)));
typedef float f32x4 __attribute__((ext_vector_type(4)));
typedef unsigned int u32x2 __attribute__((ext_vector_type(2)));
typedef unsigned int u32x4 __attribute__((ext_vector_type(4)));

__device__ __forceinline__ unsigned short f2bf(float f) {
    unsigned int u = __builtin_bit_cast(unsigned int, f);
    u += 0x7FFFu + ((u >> 16) & 1u);   // RNE
    return (unsigned short)(u >> 16);
}

// v_cvt_pk_bf16_f32: dst.lo = bf16(lo), dst.hi = bf16(hi), RNE (== f2bf pair)
__device__ __forceinline__ unsigned cvtpk(float lo, float hi) {
    unsigned r;
    asm("v_cvt_pk_bf16_f32 %0, %1, %2" : "=v"(r) : "v"(lo), "v"(hi));
    return r;
}

__device__ __forceinline__ s16x8 pack8(float4 a, float4 b) {
    s16x8 r;
    r[0] = (short)f2bf(a.x); r[1] = (short)f2bf(a.y);
    r[2] = (short)f2bf(a.z); r[3] = (short)f2bf(a.w);
    r[4] = (short)f2bf(b.x); r[5] = (short)f2bf(b.y);
    r[6] = (short)f2bf(b.z); r[7] = (short)f2bf(b.w);
    return r;
}

// d_ws layout (shorts): [0,16384) Wnnn^T [128o][128i]; [16384,24576) Wroot^T [128o][64i];
//                       [24576,40960) Wout^T [128o][128i]; [40960, +6.4M) x as bf16
__global__ void prep_w(const float* __restrict__ Wn, const float* __restrict__ Wr,
                       const float* __restrict__ Wo, unsigned short* __restrict__ wt) {
    int t = blockIdx.x * 256 + threadIdx.x;
    if (t < 16384) {
        int o = t >> 7, i = t & 127;
        wt[t] = f2bf(Wn[i * 128 + o]);
    } else if (t < 24576) {
        int q = t - 16384;
        int o = q >> 6, i = q & 63;
        wt[t] = f2bf(Wr[i * 128 + o]);
    } else if (t < 40960) {
        int q = t - 24576;
        int o = q >> 7, i = q & 127;
        wt[t] = f2bf(Wo[i * 128 + o]);
    }
}

__global__ void prep_x(const float* __restrict__ x, unsigned short* __restrict__ xb) {
    int i = blockIdx.x * 256 + threadIdx.x;    // 800000 chunks of 8 floats
    if (i < XBF_SHORTS / 8) {
        const float4* p = (const float4*)(x + (size_t)i * 8);
        *(s16x8*)(xb + (size_t)i * 8) = pack8(p[0], p[1]);
    }
}

// Swapped-operand MFMA: mfma(A = W^T frag [n][k], B = data frag [k][e]).
// C-frag: col(lane&15)=e, row((lane>>4)*4+j)=n -> 4 consecutive n per lane.
// LDS chunk-major [kq][e][8 shorts]: all accesses linear, bank-even.
// 8 waves x one 16-n slice: pinned weights = 40 VGPR/thread (proven no-spill).
// Biases pre-loaded as MFMA C-init; bf16 packing via v_cvt_pk_bf16_f32.
template<bool XBF>
__global__ __launch_bounds__(TPB, 4) void edge_mlp(
    const float* __restrict__ x, const unsigned short* __restrict__ xb,
    const int* __restrict__ eidx, const float* __restrict__ ea,
    const float* __restrict__ bn_g, const float* __restrict__ br_g,
    const float* __restrict__ bo_g,
    const unsigned short* __restrict__ wt, float* __restrict__ out)
{
    __shared__ unsigned short sh_pair[16 * 64 * 8];  // [kq][e][8], 16 KB
    __shared__ unsigned short sh_ea[8 * 64 * 8];     // [kq][e][8],  8 KB
    __shared__ unsigned short sh_hid[16 * 64 * 8];   // [kq][e][8], 16 KB

    const int tid = threadIdx.x;
    const int w   = tid >> 6;        // wave 0..7 -> n-slice w*16
    const int ln  = tid & 63;
    const int lc  = ln & 15;
    const int q   = ln >> 4;         // 0..3

    // gather ownership: thread owns edge-row r; pair chunks c0,c0+1; ea chunk ec
    const int r   = tid >> 3;        // 0..63
    const int c0  = (tid & 7) * 2;   // even chunk 0..14 (c0<8: src half, else dst)
    const int ihalf = (c0 < 8) ? 0 : E_EDGES;
    const int ec  = tid & 7;

    const unsigned short* Wn = wt;
    const unsigned short* Wr = wt + 16384;
    const unsigned short* Wo = wt + 24576;

    // --- pinned weight A-fragments (40 VGPR) ---
    s16x8 wn[4], wr[2], wo[4];
    const int n0 = w * 16 + lc;
    #pragma unroll
    for (int kk = 0; kk < 4; ++kk) wn[kk] = *(const s16x8*)(Wn + n0 * 128 + kk * 32 + q * 8);
    #pragma unroll
    for (int kk = 0; kk < 2; ++kk) wr[kk] = *(const s16x8*)(Wr + n0 * 64 + kk * 32 + q * 8);
    #pragma unroll
    for (int kk = 0; kk < 4; ++kk) wo[kk] = *(const s16x8*)(Wo + n0 * 128 + kk * 32 + q * 8);

    const int nb = w * 16 + q * 4;   // lane's 4 consecutive output features
    const f32x4 bn4 = *(const f32x4*)(bn_g + nb);
    const f32x4 br4 = *(const f32x4*)(br_g + nb);
    const f32x4 bo4 = *(const f32x4*)(bo_g + nb);

    // --- pipeline regs: tile t+1 data, tile t+2 index ---
    s16x8 pr0, pr1;                  // XBF pair chunks
    float4 pf0, pf1, pf2, pf3;       // fallback fp32 pair chunks
    f32x4 ef0, ef1;                  // ea 32B slice
    int ic, ic_n;

    int tile = blockIdx.x;
    if (tile >= NTILES) return;

    // prologue: tile-0 data, tile-1 index
    ic = eidx[ihalf + tile * BM + r];
    if constexpr (XBF) {
        const s16x8* xp = (const s16x8*)(xb + (size_t)ic * 64 + (c0 & 7) * 8);
        pr0 = xp[0]; pr1 = xp[1];
    } else {
        const float4* xp = (const float4*)(x + (size_t)ic * 64 + (c0 & 7) * 8);
        pf0 = xp[0]; pf1 = xp[1]; pf2 = xp[2]; pf3 = xp[3];
    }
    {
        const f32x4* ep = (const f32x4*)(ea + (size_t)(tile * BM + r) * 64 + ec * 8);
        ef0 = ep[0]; ef1 = ep[1];
    }
    {
        int t1 = (tile + GRID < NTILES) ? tile + GRID : tile;
        ic_n = eidx[ihalf + t1 * BM + r];
    }

    for (; tile < NTILES; tile += GRID) {
        const int base = tile * BM;
        const int tn  = (tile + GRID < NTILES) ? tile + GRID : tile;
        const int tnn = (tn + GRID < NTILES) ? tn + GRID : tn;

        // --- A: drain prefetch -> LDS (chunk-major) ---
        if constexpr (XBF) {
            *(s16x8*)((char*)sh_pair + c0 * 1024 + r * 16)       = pr0;
            *(s16x8*)((char*)sh_pair + (c0 + 1) * 1024 + r * 16) = pr1;
        } else {
            *(s16x8*)((char*)sh_pair + c0 * 1024 + r * 16)       = pack8(pf0, pf1);
            *(s16x8*)((char*)sh_pair + (c0 + 1) * 1024 + r * 16) = pack8(pf2, pf3);
        }
        {
            u32x4 v;
            v[0] = cvtpk(ef0[0], ef0[1]);
            v[1] = cvtpk(ef0[2], ef0[3]);
            v[2] = cvtpk(ef1[0], ef1[1]);
            v[3] = cvtpk(ef1[2], ef1[3]);
            *(u32x4*)((char*)sh_ea + ec * 1024 + r * 16) = v;
        }

        // --- C: issue tile t+1 loads (cover: D + barrier + E) ---
        ic = ic_n;
        if constexpr (XBF) {
            const s16x8* xp = (const s16x8*)(xb + (size_t)ic * 64 + (c0 & 7) * 8);
            pr0 = xp[0]; pr1 = xp[1];
        } else {
            const float4* xp = (const float4*)(x + (size_t)ic * 64 + (c0 & 7) * 8);
            pf0 = xp[0]; pf1 = xp[1]; pf2 = xp[2]; pf3 = xp[3];
        }
        {
            const f32x4* ep = (const f32x4*)(ea + (size_t)(tn * BM + r) * 64 + ec * 8);
            ef0 = ep[0]; ef1 = ep[1];
        }
        ic_n = eidx[ihalf + tnn * BM + r];   // tile t+2 index (full-tile cover)

        __syncthreads();   // barrier1: pair/ea ready; hid E(t-1) reads done

        // --- D: layer 1 -> sh_hid (bias as C-init) ---
        #pragma unroll
        for (int m = 0; m < 4; ++m) {
            const int e = m * 16 + lc;
            f32x4 a1 = bn4;
            f32x4 a2 = br4;
            #pragma unroll
            for (int kk = 0; kk < 4; ++kk) {
                s16x8 g = *(const s16x8*)((const char*)sh_pair + (kk * 4 + q) * 1024 + e * 16);
                a1 = __builtin_amdgcn_mfma_f32_16x16x32_bf16(wn[kk], g, a1, 0, 0, 0);
            }
            #pragma unroll
            for (int kk = 0; kk < 2; ++kk) {
                s16x8 g = *(const s16x8*)((const char*)sh_ea + (kk * 4 + q) * 1024 + e * 16);
                a2 = __builtin_amdgcn_mfma_f32_16x16x32_bf16(wr[kk], g, a2, 0, 0, 0);
            }
            float h0 = fmaxf(a1[0], 0.f) + fmaxf(a2[0], 0.f);
            float h1 = fmaxf(a1[1], 0.f) + fmaxf(a2[1], 0.f);
            float h2 = fmaxf(a1[2], 0.f) + fmaxf(a2[2], 0.f);
            float h3 = fmaxf(a1[3], 0.f) + fmaxf(a2[3], 0.f);
            u32x2 hv;
            hv[0] = cvtpk(h0, h1);
            hv[1] = cvtpk(h2, h3);
            // n0 = w*16+q*4 -> chunk = w*2+(q>>1), byte-in-row = (q&1)*8
            *(u32x2*)((char*)sh_hid + (w * 2 + (q >> 1)) * 1024 + e * 16 + (q & 1) * 8) = hv;
        }
        __syncthreads();   // barrier2: hid ready; pair/ea reads done before A(t+1)

        // --- E: layer 2 -> out (bias as C-init) ---
        #pragma unroll
        for (int m = 0; m < 4; ++m) {
            const int e = m * 16 + lc;
            f32x4 a3 = bo4;
            #pragma unroll
            for (int kk = 0; kk < 4; ++kk) {
                s16x8 g = *(const s16x8*)((const char*)sh_hid + (kk * 4 + q) * 1024 + e * 16);
                a3 = __builtin_amdgcn_mfma_f32_16x16x32_bf16(wo[kk], g, a3, 0, 0, 0);
            }
            f32x4 o;
            o[0] = fmaxf(a3[0], 0.f);
            o[1] = fmaxf(a3[1], 0.f);
            o[2] = fmaxf(a3[2], 0.f);
            o[3] = fmaxf(a3[3], 0.f);
            *(f32x4*)(out + (size_t)(base + e) * 128 + nb) = o;
        }
    }
}

extern "C" void kernel_launch(void* const* d_in, const int* in_sizes, int n_in,
                              void* d_out, int out_size, void* d_ws, size_t ws_size,
                              hipStream_t stream) {
    const float* x   = (const float*)d_in[0];
    const int*   ei  = (const int*)d_in[1];
    const float* ea  = (const float*)d_in[2];
    const float* Wn  = (const float*)d_in[3];
    const float* bn  = (const float*)d_in[4];
    const float* Wr  = (const float*)d_in[5];
    const float* br  = (const float*)d_in[6];
    const float* Wo  = (const float*)d_in[7];
    const float* bo  = (const float*)d_in[8];
    float* out = (float*)d_out;
    unsigned short* wt = (unsigned short*)d_ws;

    const bool xbf = ws_size >= (size_t)(WOFF + XBF_SHORTS) * sizeof(unsigned short);

    prep_w<<<160, 256, 0, stream>>>(Wn, Wr, Wo, wt);
    if (xbf) {
        prep_x<<<XBF_SHORTS / 8 / 256, 256, 0, stream>>>(x, wt + WOFF);
        edge_mlp<true><<<GRID, TPB, 0, stream>>>(x, wt + WOFF, ei, ea, bn, br, bo, wt, out);
    } else {
        edge_mlp<false><<<GRID, TPB, 0, stream>>>(x, nullptr, ei, ea, bn, br, bo, wt, out);
    }
}

// Round 13
// 280.777 us; speedup vs baseline: 1.7217x; 1.0420x over previous
//
#include <hip/hip_runtime.h>

#define E_EDGES 1600000
#define BM 64
#define TPB 256
#define NTILES (E_EDGES / BM)   // 25000 exactly
#define GRID 768
#define WOFF 40960              // shorts reserved for weights in d_ws
#define XBF_SHORTS (100000 * 64)

typedef short s16x8 __attribute__((ext_vector_type(8)));
typedef float f32x4 __attribute__((ext_vector_type(4)));
typedef unsigned int u32x2 __attribute__((ext_vector_type(2)));
typedef unsigned int u32x4 __attribute__((ext_vector_type(4)));

__device__ __forceinline__ unsigned short f2bf(float f) {
    unsigned int u = __builtin_bit_cast(unsigned int, f);
    u += 0x7FFFu + ((u >> 16) & 1u);   // RNE
    return (unsigned short)(u >> 16);
}

// v_cvt_pk_bf16_f32: dst.lo = bf16(lo), dst.hi = bf16(hi), RNE (== f2bf pair)
__device__ __forceinline__ unsigned cvtpk(float lo, float hi) {
    unsigned r;
    asm("v_cvt_pk_bf16_f32 %0, %1, %2" : "=v"(r) : "v"(lo), "v"(hi));
    return r;
}

__device__ __forceinline__ s16x8 pack8(float4 a, float4 b) {
    s16x8 r;
    r[0] = (short)f2bf(a.x); r[1] = (short)f2bf(a.y);
    r[2] = (short)f2bf(a.z); r[3] = (short)f2bf(a.w);
    r[4] = (short)f2bf(b.x); r[5] = (short)f2bf(b.y);
    r[6] = (short)f2bf(b.z); r[7] = (short)f2bf(b.w);
    return r;
}

// d_ws layout (shorts): [0,16384) Wnnn^T [128o][128i]; [16384,24576) Wroot^T [128o][64i];
//                       [24576,40960) Wout^T [128o][128i]; [40960, +6.4M) x as bf16
__global__ void prep_w(const float* __restrict__ Wn, const float* __restrict__ Wr,
                       const float* __restrict__ Wo, unsigned short* __restrict__ wt) {
    int t = blockIdx.x * 256 + threadIdx.x;
    if (t < 16384) {
        int o = t >> 7, i = t & 127;
        wt[t] = f2bf(Wn[i * 128 + o]);
    } else if (t < 24576) {
        int q = t - 16384;
        int o = q >> 6, i = q & 63;
        wt[t] = f2bf(Wr[i * 128 + o]);
    } else if (t < 40960) {
        int q = t - 24576;
        int o = q >> 7, i = q & 127;
        wt[t] = f2bf(Wo[i * 128 + o]);
    }
}

__global__ void prep_x(const float* __restrict__ x, unsigned short* __restrict__ xb) {
    int i = blockIdx.x * 256 + threadIdx.x;    // 800000 chunks of 8 floats
    if (i < XBF_SHORTS / 8) {
        const float4* p = (const float4*)(x + (size_t)i * 8);
        *(s16x8*)(xb + (size_t)i * 8) = pack8(p[0], p[1]);
    }
}

// Swapped-operand MFMA: mfma(A = W^T frag [n][k], B = data frag [k][e]).
// C-frag: col(lane&15)=e, row((lane>>4)*4+j)=n -> 4 consecutive n per lane.
// LDS chunk-major [kq][e][8 shorts]: all accesses linear, bank-even.
// nt=2 n-blocking: 4 waves, wave w owns n in [w*32,w*32+32) as two 16-n
// subtiles -> every LDS B-frag read feeds TWO MFMAs (halves D/E LDS reads).
// launch_bounds(256,2): min-occupancy 2 waves/EU -> reg cap 256; natural
// demand ~155 -> 3 waves/EU, NO forced spill (R11 failure mode avoided).
template<bool XBF>
__global__ __launch_bounds__(TPB, 2) void edge_mlp(
    const float* __restrict__ x, const unsigned short* __restrict__ xb,
    const int* __restrict__ eidx, const float* __restrict__ ea,
    const float* __restrict__ bn_g, const float* __restrict__ br_g,
    const float* __restrict__ bo_g,
    const unsigned short* __restrict__ wt, float* __restrict__ out)
{
    __shared__ unsigned short sh_pair[16 * 64 * 8];  // [kq][e][8], 16 KB
    __shared__ unsigned short sh_ea[8 * 64 * 8];     // [kq][e][8],  8 KB
    __shared__ unsigned short sh_hid[16 * 64 * 8];   // [kq][e][8], 16 KB

    const int tid = threadIdx.x;
    const int w   = tid >> 6;        // wave 0..3 -> n in [w*32, w*32+32)
    const int ln  = tid & 63;
    const int lc  = ln & 15;
    const int q   = ln >> 4;         // 0..3

    // gather ownership: thread owns edge-row r; pair quarter sub (4 chunks = 64B
    // of one node's half-row); ea 64B slice es
    const int r   = tid >> 2;        // 0..63
    const int sub = tid & 3;         // 0,1: src halves; 2,3: dst halves
    const int ihalf = (sub < 2) ? 0 : E_EDGES;
    const int xo  = (sub & 1) * 32;  // short offset within node row
    const int es  = tid & 3;

    const unsigned short* Wn = wt;
    const unsigned short* Wr = wt + 16384;
    const unsigned short* Wo = wt + 24576;

    // --- pinned weight A-fragments (80 VGPR) ---
    s16x8 wn[2][4], wr[2][2], wo[2][4];
    #pragma unroll
    for (int nt = 0; nt < 2; ++nt) {
        const int n0 = w * 32 + nt * 16 + lc;
        #pragma unroll
        for (int kk = 0; kk < 4; ++kk) wn[nt][kk] = *(const s16x8*)(Wn + n0 * 128 + kk * 32 + q * 8);
        #pragma unroll
        for (int kk = 0; kk < 2; ++kk) wr[nt][kk] = *(const s16x8*)(Wr + n0 * 64 + kk * 32 + q * 8);
        #pragma unroll
        for (int kk = 0; kk < 4; ++kk) wo[nt][kk] = *(const s16x8*)(Wo + n0 * 128 + kk * 32 + q * 8);
    }
    // biases as f32x4 C-init (12 VGPR)
    f32x4 bn4[2], br4[2], bo4[2];
    #pragma unroll
    for (int nt = 0; nt < 2; ++nt) {
        const int nb = w * 32 + nt * 16 + q * 4;
        bn4[nt] = *(const f32x4*)(bn_g + nb);
        br4[nt] = *(const f32x4*)(br_g + nb);
        bo4[nt] = *(const f32x4*)(bo_g + nb);
    }

    // --- pipeline regs: tile t+1 data, tile t+2 index ---
    s16x8 pr[4];                     // XBF: 64B contiguous slice of node row
    float4 pf[8];                    // fallback: 128B fp32 slice
    f32x4 ef[4];                     // ea 64B slice
    int ic, ic_n;

    int tile = blockIdx.x;

    // prologue: tile-0 data, tile-1 index
    ic = eidx[ihalf + tile * BM + r];
    if constexpr (XBF) {
        const s16x8* xp = (const s16x8*)(xb + (size_t)ic * 64 + xo);
        #pragma unroll
        for (int k = 0; k < 4; ++k) pr[k] = xp[k];
    } else {
        const float4* xp = (const float4*)(x + (size_t)ic * 64 + xo);
        #pragma unroll
        for (int k = 0; k < 8; ++k) pf[k] = xp[k];
    }
    {
        const f32x4* ep = (const f32x4*)(ea + (size_t)(tile * BM + r) * 64 + es * 16);
        #pragma unroll
        for (int k = 0; k < 4; ++k) ef[k] = ep[k];
    }
    {
        int t1 = (tile + GRID < NTILES) ? tile + GRID : tile;
        ic_n = eidx[ihalf + t1 * BM + r];
    }

    for (; tile < NTILES; tile += GRID) {
        const int base = tile * BM;
        const int tn  = (tile + GRID < NTILES) ? tile + GRID : tile;
        const int tnn = (tn + GRID < NTILES) ? tn + GRID : tn;

        // --- A: drain prefetch -> LDS (chunk-major) ---
        if constexpr (XBF) {
            #pragma unroll
            for (int i = 0; i < 4; ++i)
                *(s16x8*)((char*)sh_pair + (sub * 4 + i) * 1024 + r * 16) = pr[i];
        } else {
            #pragma unroll
            for (int i = 0; i < 4; ++i)
                *(s16x8*)((char*)sh_pair + (sub * 4 + i) * 1024 + r * 16) = pack8(pf[2 * i], pf[2 * i + 1]);
        }
        #pragma unroll
        for (int i = 0; i < 2; ++i) {
            u32x4 v;
            v[0] = cvtpk(ef[2 * i][0], ef[2 * i][1]);
            v[1] = cvtpk(ef[2 * i][2], ef[2 * i][3]);
            v[2] = cvtpk(ef[2 * i + 1][0], ef[2 * i + 1][1]);
            v[3] = cvtpk(ef[2 * i + 1][2], ef[2 * i + 1][3]);
            *(u32x4*)((char*)sh_ea + (es * 2 + i) * 1024 + r * 16) = v;
        }

        // --- C: issue tile t+1 loads (latency hidden under D+E) ---
        ic = ic_n;
        if constexpr (XBF) {
            const s16x8* xp = (const s16x8*)(xb + (size_t)ic * 64 + xo);
            #pragma unroll
            for (int k = 0; k < 4; ++k) pr[k] = xp[k];
        } else {
            const float4* xp = (const float4*)(x + (size_t)ic * 64 + xo);
            #pragma unroll
            for (int k = 0; k < 8; ++k) pf[k] = xp[k];
        }
        {
            const f32x4* ep = (const f32x4*)(ea + (size_t)(tn * BM + r) * 64 + es * 16);
            #pragma unroll
            for (int k = 0; k < 4; ++k) ef[k] = ep[k];
        }
        ic_n = eidx[ihalf + tnn * BM + r];

        __syncthreads();   // barrier1: pair/ea ready; hid E(t-1) reads done

        // --- D: layer 1 -> sh_hid (bias as C-init) ---
        #pragma unroll
        for (int m = 0; m < 4; ++m) {
            const int e = m * 16 + lc;
            s16x8 g0 = *(const s16x8*)((const char*)sh_pair + (0 * 4 + q) * 1024 + e * 16);
            s16x8 g1 = *(const s16x8*)((const char*)sh_pair + (1 * 4 + q) * 1024 + e * 16);
            s16x8 g2 = *(const s16x8*)((const char*)sh_pair + (2 * 4 + q) * 1024 + e * 16);
            s16x8 g3 = *(const s16x8*)((const char*)sh_pair + (3 * 4 + q) * 1024 + e * 16);
            s16x8 e0 = *(const s16x8*)((const char*)sh_ea + (0 * 4 + q) * 1024 + e * 16);
            s16x8 e1 = *(const s16x8*)((const char*)sh_ea + (1 * 4 + q) * 1024 + e * 16);
            f32x4 a1[2], a2[2];
            #pragma unroll
            for (int nt = 0; nt < 2; ++nt) { a1[nt] = bn4[nt]; a2[nt] = br4[nt]; }
            #pragma unroll
            for (int nt = 0; nt < 2; ++nt) {
                a1[nt] = __builtin_amdgcn_mfma_f32_16x16x32_bf16(wn[nt][0], g0, a1[nt], 0, 0, 0);
                a1[nt] = __builtin_amdgcn_mfma_f32_16x16x32_bf16(wn[nt][1], g1, a1[nt], 0, 0, 0);
                a1[nt] = __builtin_amdgcn_mfma_f32_16x16x32_bf16(wn[nt][2], g2, a1[nt], 0, 0, 0);
                a1[nt] = __builtin_amdgcn_mfma_f32_16x16x32_bf16(wn[nt][3], g3, a1[nt], 0, 0, 0);
                a2[nt] = __builtin_amdgcn_mfma_f32_16x16x32_bf16(wr[nt][0], e0, a2[nt], 0, 0, 0);
                a2[nt] = __builtin_amdgcn_mfma_f32_16x16x32_bf16(wr[nt][1], e1, a2[nt], 0, 0, 0);
            }
            #pragma unroll
            for (int nt = 0; nt < 2; ++nt) {
                float h0 = fmaxf(a1[nt][0], 0.f) + fmaxf(a2[nt][0], 0.f);
                float h1 = fmaxf(a1[nt][1], 0.f) + fmaxf(a2[nt][1], 0.f);
                float h2 = fmaxf(a1[nt][2], 0.f) + fmaxf(a2[nt][2], 0.f);
                float h3 = fmaxf(a1[nt][3], 0.f) + fmaxf(a2[nt][3], 0.f);
                u32x2 hv;
                hv[0] = cvtpk(h0, h1);
                hv[1] = cvtpk(h2, h3);
                // n0 = w*32+nt*16+q*4 -> chunk = w*4+nt*2+(q>>1), byte = (q&1)*8
                *(u32x2*)((char*)sh_hid + (w * 4 + nt * 2 + (q >> 1)) * 1024 + e * 16 + (q & 1) * 8) = hv;
            }
        }
        __syncthreads();   // barrier2: hid ready; pair/ea reads done before A(t+1)

        // --- E: layer 2 -> out (bias as C-init) ---
        #pragma unroll
        for (int m = 0; m < 4; ++m) {
            const int e = m * 16 + lc;
            s16x8 g0 = *(const s16x8*)((const char*)sh_hid + (0 * 4 + q) * 1024 + e * 16);
            s16x8 g1 = *(const s16x8*)((const char*)sh_hid + (1 * 4 + q) * 1024 + e * 16);
            s16x8 g2 = *(const s16x8*)((const char*)sh_hid + (2 * 4 + q) * 1024 + e * 16);
            s16x8 g3 = *(const s16x8*)((const char*)sh_hid + (3 * 4 + q) * 1024 + e * 16);
            f32x4 a3[2];
            #pragma unroll
            for (int nt = 0; nt < 2; ++nt) a3[nt] = bo4[nt];
            #pragma unroll
            for (int nt = 0; nt < 2; ++nt) {
                a3[nt] = __builtin_amdgcn_mfma_f32_16x16x32_bf16(wo[nt][0], g0, a3[nt], 0, 0, 0);
                a3[nt] = __builtin_amdgcn_mfma_f32_16x16x32_bf16(wo[nt][1], g1, a3[nt], 0, 0, 0);
                a3[nt] = __builtin_amdgcn_mfma_f32_16x16x32_bf16(wo[nt][2], g2, a3[nt], 0, 0, 0);
                a3[nt] = __builtin_amdgcn_mfma_f32_16x16x32_bf16(wo[nt][3], g3, a3[nt], 0, 0, 0);
            }
            #pragma unroll
            for (int nt = 0; nt < 2; ++nt) {
                f32x4 o;
                o[0] = fmaxf(a3[nt][0], 0.f);
                o[1] = fmaxf(a3[nt][1], 0.f);
                o[2] = fmaxf(a3[nt][2], 0.f);
                o[3] = fmaxf(a3[nt][3], 0.f);
                *(f32x4*)(out + (size_t)(base + e) * 128 + w * 32 + nt * 16 + q * 4) = o;
            }
        }
    }
}

extern "C" void kernel_launch(void* const* d_in, const int* in_sizes, int n_in,
                              void* d_out, int out_size, void* d_ws, size_t ws_size,
                              hipStream_t stream) {
    const float* x   = (const float*)d_in[0];
    const int*   ei  = (const int*)d_in[1];
    const float* ea  = (const float*)d_in[2];
    const float* Wn  = (const float*)d_in[3];
    const float* bn  = (const float*)d_in[4];
    const float* Wr  = (const float*)d_in[5];
    const float* br  = (const float*)d_in[6];
    const float* Wo  = (const float*)d_in[7];
    const float* bo  = (const float*)d_in[8];
    float* out = (float*)d_out;
    unsigned short* wt = (unsigned short*)d_ws;

    const bool xbf = ws_size >= (size_t)(WOFF + XBF_SHORTS) * sizeof(unsigned short);

    prep_w<<<160, 256, 0, stream>>>(Wn, Wr, Wo, wt);
    if (xbf) {
        prep_x<<<XBF_SHORTS / 8 / 256, 256, 0, stream>>>(x, wt + WOFF);
        edge_mlp<true><<<GRID, TPB, 0, stream>>>(x, wt + WOFF, ei, ea, bn, br, bo, wt, out);
    } else {
        edge_mlp<false><<<GRID, TPB, 0, stream>>>(x, nullptr, ei, ea, bn, br, bo, wt, out);
    }
}